// Round 6
// baseline (260.085 us; speedup 1.0000x reference)
//
#include <hip/hip_runtime.h>

typedef unsigned short u16;
typedef unsigned int   u32;

typedef short bf16x8 __attribute__((ext_vector_type(8)));
typedef float f32x4  __attribute__((ext_vector_type(4)));

__device__ __forceinline__ float bf2f(u16 u) { return __uint_as_float(((u32)u) << 16); }
__device__ __forceinline__ u16 f2bf(float f) {
    u32 u = __float_as_uint(f);
    return (u16)((u + 0x7fffu + ((u >> 16) & 1u)) >> 16);
}

#define MFMA16(a, b, c) __builtin_amdgcn_mfma_f32_16x16x32_bf16(a, b, c, 0, 0, 0)

// ---------------------------------------------------------------------------
// K0: transpose x[b][ci][p] fp32 -> xT[b][p][ci] bf16.
// ---------------------------------------------------------------------------
__global__ __launch_bounds__(256, 4) void k_xpose(const float* __restrict__ x,
                                                  u16* __restrict__ xT) {
    __shared__ u16 Xs[128 * 128];
    const int ptile = blockIdx.x, b = blockIdx.y;
    const int t = threadIdx.x;
    const float* xb = x + (((size_t)b) << 21) + ptile * 128;
#pragma unroll
    for (int i = 0; i < 16; ++i) {
        int idx = i * 256 + t;
        int ci = idx >> 5, pq = idx & 31;
        float4 v = *(const float4*)(xb + (((size_t)ci) << 14) + pq * 4);
        u32 lo = (u32)f2bf(v.x) | ((u32)f2bf(v.y) << 16);
        u32 hi = (u32)f2bf(v.z) | ((u32)f2bf(v.w) << 16);
        uint2 pk; pk.x = lo; pk.y = hi;
        int cq = ci >> 3;
        *(uint2*)(&Xs[ci * 128 + ((pq ^ cq) << 2)]) = pk;
    }
    __syncthreads();
    u16* ob = xT + (((size_t)b) << 21) + ((size_t)(ptile * 128)) * 128;
#pragma unroll
    for (int j = 0; j < 8; ++j) {
        int p = j * 16 + (t >> 4), cq = t & 15;
        u16 tmp[8];
#pragma unroll
        for (int c = 0; c < 8; ++c) {
            int ci = cq * 8 + c;
            tmp[c] = Xs[ci * 128 + (((p >> 2) ^ cq) << 2) + (p & 3)];
        }
        *(uint4*)(&ob[(size_t)p * 128 + cq * 8]) = *(const uint4*)tmp;
    }
}

// ---------------------------------------------------------------------------
// K1 v2: qkv 1x1 conv from xT.  Block = (h, b), M=384 via temporal cg-loop:
// B-tile (swizzled, 32 KB) staged ONCE, reused for cg=0..2; acc stays 32 VGPR;
// Cs (34 KB) reused per cg with sync pairs.  66 KB LDS -> 2 blocks/CU.
// ---------------------------------------------------------------------------
__global__ __launch_bounds__(512, 4) void k_qkv(const u16* __restrict__ xT,
                                                const float* __restrict__ w,
                                                const float* __restrict__ bias,
                                                u16* __restrict__ out1) {
    extern __shared__ char smem[];
    u16* Bt = (u16*)smem;            // 32 KB swizzled [p][g]
    u16* Cs = Bt + 2048 * 8;         // [128 co][136 p]
    const int h = blockIdx.x, b = blockIdx.y;
    const int t = threadIdx.x;

    const u16* xb = xT + (((size_t)b) << 21) + ((size_t)(h * 128)) * 128;
#pragma unroll
    for (int i = 0; i < 4; ++i) {
        int slot = i * 512 + t;
        int p = slot >> 4, g = slot & 15;
        int gg = g ^ (p & 15);
        uint4 v = *(const uint4*)(&xb[p * 128 + gg * 8]);
        *(uint4*)(&Bt[slot * 8]) = v;
    }
    __syncthreads();

    const int wave = t >> 6, lane = t & 63, m16 = lane & 15, quad = lane >> 4;

    for (int cg = 0; cg < 3; ++cg) {
        // A fragments for this cg (fp32 -> bf16)
        bf16x8 afr[4];
        const float* wp0 = w + (size_t)(cg * 128 + wave * 16 + m16) * 128 + quad * 8;
#pragma unroll
        for (int kk = 0; kk < 4; ++kk) {
            float4 w0 = *(const float4*)(wp0 + kk * 32);
            float4 w1 = *(const float4*)(wp0 + kk * 32 + 4);
            bf16x8 a;
            a[0] = (short)f2bf(w0.x); a[1] = (short)f2bf(w0.y);
            a[2] = (short)f2bf(w0.z); a[3] = (short)f2bf(w0.w);
            a[4] = (short)f2bf(w1.x); a[5] = (short)f2bf(w1.y);
            a[6] = (short)f2bf(w1.z); a[7] = (short)f2bf(w1.w);
            afr[kk] = a;
        }

        f32x4 acc[8] = {};
#pragma unroll
        for (int kk = 0; kk < 4; ++kk) {
            const int g = kk * 4 + quad;
#pragma unroll
            for (int nt = 0; nt < 8; ++nt) {
                int p = nt * 16 + m16;
                bf16x8 bf = *(const bf16x8*)(&Bt[p * 128 + ((g ^ (p & 15)) << 3)]);
                acc[nt] = MFMA16(afr[kk], bf, acc[nt]);
            }
        }

        float bv[4];
#pragma unroll
        for (int r = 0; r < 4; ++r) bv[r] = bias[cg * 128 + wave * 16 + quad * 4 + r];

        __syncthreads();   // prior store-phase reads of Cs complete
#pragma unroll
        for (int nt = 0; nt < 8; ++nt) {
            int p = nt * 16 + m16;
#pragma unroll
            for (int r = 0; r < 4; ++r)
                Cs[(wave * 16 + quad * 4 + r) * 136 + p] = f2bf(acc[nt][r] + bv[r]);
        }
        __syncthreads();

        u16* ob = out1 + (((size_t)(b * 384 + cg * 128)) << 14) + (h << 7);
#pragma unroll
        for (int it = 0; it < 4; ++it) {
            int idx = it * 512 + t;
            int co = idx >> 4, cp = idx & 15;
            *(uint4*)(&ob[((size_t)co << 14) + cp * 8]) = *(const uint4*)(&Cs[co * 136 + cp * 8]);
        }
    }
}

// ---------------------------------------------------------------------------
// K2: depthwise 3x3 (LDS-tiled).
// ---------------------------------------------------------------------------
__global__ __launch_bounds__(256, 4) void k_dw(const u16* __restrict__ in,
                                               const float* __restrict__ w,
                                               const float* __restrict__ bias,
                                               u16* __restrict__ out) {
    __shared__ u16 tile[34 * 144];
    const int htile = blockIdx.x;
    const int ch = blockIdx.y;
    const int b = blockIdx.z;
    const int t = threadIdx.x;
    const u16* base = in + (((size_t)(b * 384 + ch)) << 14);

    if (t < 68) {
        int r = t >> 1, side = t & 1;
        uint4 z = {0, 0, 0, 0};
        *(uint4*)(&tile[r * 144 + side * 136]) = z;
    }
    for (int it = 0; it < 3; ++it) {
        int idx = it * 256 + t;
        if (idx < 544) {
            int r = idx >> 4, cq = idx & 15;
            int y = htile * 32 - 1 + r;
            uint4 v = {0, 0, 0, 0};
            if (y >= 0 && y <= 127) v = *(const uint4*)(base + (y << 7) + cq * 8);
            *(uint4*)(&tile[r * 144 + 8 + cq * 8]) = v;
        }
    }
    float wg[9];
#pragma unroll
    for (int i = 0; i < 9; ++i) wg[i] = w[ch * 9 + i];
    const float bv = bias[ch];
    __syncthreads();

    const int r = t >> 4, cp = t & 15, c0 = cp * 8;
    u16* ob = out + (((size_t)(b * 384 + ch)) << 14) + ((htile * 32) << 7) + c0;
#pragma unroll
    for (int half = 0; half < 2; ++half) {
        const int ro = r + half * 16;
        float acc[8];
#pragma unroll
        for (int c = 0; c < 8; ++c) acc[c] = bv;
#pragma unroll
        for (int dy = 0; dy < 3; ++dy) {
            const u16* row = &tile[(ro + dy) * 144 + 8 + c0];
            float v[10];
            v[0] = bf2f(row[-1]);
            uint4 m = *(const uint4*)row;
            v[1] = bf2f((u16)(m.x & 0xffff)); v[2] = bf2f((u16)(m.x >> 16));
            v[3] = bf2f((u16)(m.y & 0xffff)); v[4] = bf2f((u16)(m.y >> 16));
            v[5] = bf2f((u16)(m.z & 0xffff)); v[6] = bf2f((u16)(m.z >> 16));
            v[7] = bf2f((u16)(m.w & 0xffff)); v[8] = bf2f((u16)(m.w >> 16));
            v[9] = bf2f(row[8]);
#pragma unroll
            for (int dx = 0; dx < 3; ++dx) {
                const float wv = wg[dy * 3 + dx];
#pragma unroll
                for (int c = 0; c < 8; ++c) acc[c] += wv * v[c + dx];
            }
        }
        u32 pk[4];
#pragma unroll
        for (int c2 = 0; c2 < 4; ++c2) {
            u32 lo = f2bf(acc[2 * c2]), hi = f2bf(acc[2 * c2 + 1]);
            pk[c2] = lo | (hi << 16);
        }
        *(uint4*)(ob + (ro << 7)) = *(uint4*)pk;
    }
}

// ---------------------------------------------------------------------------
// K3 v2: per-(b,ch) attention.  512 thr / 8 waves, 76 KB LDS -> 2 blocks/CU.
// ---------------------------------------------------------------------------
__global__ __launch_bounds__(512, 4) void k_attn(const u16* __restrict__ qkv,
                                                 const float* __restrict__ temp,
                                                 u16* __restrict__ outp) {
    extern __shared__ char smem[];
    u16* Qt = (u16*)smem;            // [j][i] swizzled; Pt aliases
    u16* Kt = Qt + 16384;            // [k][i] swizzled; Osh aliases
    u16* Sg = Qt + 32768;            // [32][144] staging
    float* ps = (float*)(smem + 74752);   // [4][128]
    float* rq = (float*)(smem + 76800);   // [128]
    float* rk = (float*)(smem + 77312);   // [128]
    u16* Pt = Qt;
    u16* Osh = Kt;

    const int ch = blockIdx.x, b = blockIdx.y;
    const int head = ch >> 5;
    const int t = threadIdx.x;
    const size_t qoff = ((size_t)(b * 384 + ch)) << 14;
    const size_t koff = ((size_t)(b * 384 + 128 + ch)) << 14;
    const size_t voff = ((size_t)(b * 384 + 256 + ch)) << 14;

    const int wave = t >> 6, lane = t & 63, m16 = lane & 15, quad = lane >> 4;

    bf16x8 vfr[4];
    {
        const u16* vrow = qkv + voff + (size_t)(wave * 16 + m16) * 128 + quad * 8;
#pragma unroll
        for (int kk = 0; kk < 4; ++kk)
            vfr[kk] = *(const bf16x8*)(vrow + kk * 32);
    }

    const int ldr = t >> 4, ldj8 = t & 15;
    const size_t ldsrc = (ldr < 16 ? qoff + (size_t)ldr * 128
                                   : koff + (size_t)(ldr - 16) * 128) + ldj8 * 8;
    const int gmat = t >> 8, gig = (t >> 7) & 1, gj = t & 127;
    const u16* gcol = &Sg[(gmat * 16 + gig * 8) * 144 + gj];
    u16* gdstbase = (gmat ? Kt : Qt) + gj * 128;
    float ssq = 0.f;
#pragma unroll
    for (int p = 0; p < 8; ++p) {
        *(uint4*)(&Sg[ldr * 144 + ldj8 * 8]) = *(const uint4*)(&qkv[ldsrc + (size_t)p * 2048]);
        __syncthreads();
        u16 tmp[8];
#pragma unroll
        for (int c = 0; c < 8; ++c) {
            u16 v = gcol[c * 144];
            tmp[c] = v;
            float f = bf2f(v);
            ssq += f * f;
        }
        int g = p * 2 + gig;
        *(uint4*)(gdstbase + ((g ^ (gj & 15)) << 3)) = *(const uint4*)tmp;
        __syncthreads();
    }
    ps[(gmat * 2 + gig) * 128 + gj] = ssq;
    __syncthreads();
    if (t < 256) {
        int mat = t >> 7, j = t & 127;
        float s = ps[(mat * 2) * 128 + j] + ps[(mat * 2 + 1) * 128 + j];
        float r = 1.0f / fmaxf(sqrtf(s), 1e-12f);
        if (mat == 0) rq[j] = r; else rk[j] = r;
    }
    __syncthreads();

    f32x4 S[8] = {};
#pragma unroll
    for (int kk = 0; kk < 4; ++kk) {
        const int sw = ((kk * 4 + quad) ^ m16) << 3;
        bf16x8 bf = *(const bf16x8*)(&Kt[(wave * 16 + m16) * 128 + sw]);
#pragma unroll
        for (int jt = 0; jt < 8; ++jt) {
            bf16x8 af = *(const bf16x8*)(&Qt[(jt * 16 + m16) * 128 + sw]);
            S[jt] = MFMA16(af, bf, S[jt]);
        }
    }

    const float sc = temp[head] * rk[wave * 16 + m16];
    float vals[8][4];
    float vmax = -1e30f;
#pragma unroll
    for (int jt = 0; jt < 8; ++jt)
#pragma unroll
        for (int r = 0; r < 4; ++r) {
            float v = S[jt][r] * (rq[jt * 16 + quad * 4 + r] * sc);
            vals[jt][r] = v;
            vmax = fmaxf(vmax, v);
        }
    vmax = fmaxf(vmax, __shfl_xor(vmax, 16));
    vmax = fmaxf(vmax, __shfl_xor(vmax, 32));
    float sum = 0.f;
#pragma unroll
    for (int jt = 0; jt < 8; ++jt)
#pragma unroll
        for (int r = 0; r < 4; ++r) {
            float e = __expf(vals[jt][r] - vmax);
            vals[jt][r] = e;
            sum += e;
        }
    sum += __shfl_xor(sum, 16);
    sum += __shfl_xor(sum, 32);
    const float inv = 1.0f / sum;

    __syncthreads();

    {
        const int k = wave * 16 + m16;
        u16* prow = Pt + k * 128;
#pragma unroll
        for (int jt = 0; jt < 8; ++jt)
#pragma unroll
            for (int pr = 0; pr < 2; ++pr) {
                int j0 = jt * 16 + quad * 4 + pr * 2;
                u32 pk = (u32)f2bf(vals[jt][pr * 2] * inv) |
                         ((u32)f2bf(vals[jt][pr * 2 + 1] * inv) << 16);
                *(u32*)(prow + (((j0 >> 3) ^ (k & 15)) << 3) + (j0 & 7)) = pk;
            }
    }
    __syncthreads();

    f32x4 O[8] = {};
#pragma unroll
    for (int kk = 0; kk < 4; ++kk) {
        const int sw = ((kk * 4 + quad) ^ m16) << 3;
#pragma unroll
        for (int nt = 0; nt < 8; ++nt) {
            bf16x8 bf = *(const bf16x8*)(&Pt[(nt * 16 + m16) * 128 + sw]);
            O[nt] = MFMA16(vfr[kk], bf, O[nt]);
        }
    }

#pragma unroll
    for (int nt = 0; nt < 8; ++nt) {
        int k = nt * 16 + m16;
#pragma unroll
        for (int r = 0; r < 4; ++r) {
            int i = wave * 16 + quad * 4 + r;
            Osh[i * 128 + (((k >> 3) ^ (i & 15)) << 3) + (k & 7)] = f2bf(O[nt][r]);
        }
    }
    __syncthreads();

    u16* ob = outp + (((size_t)(b * 128 + ch)) << 14);
#pragma unroll
    for (int it = 0; it < 4; ++it) {
        int idx = it * 512 + t;
        int row = idx >> 4, gk = idx & 15;
        uint4 v = *(const uint4*)(&Osh[row * 128 + ((gk ^ (row & 15)) << 3)]);
        *(uint4*)(&ob[(row << 7) + gk * 8]) = v;
    }
}

// ---------------------------------------------------------------------------
// K4 v2: proj 1x1 conv.  Block (h,b).  Staged-panel gather transpose into
// swizzled 32 KB tile (conflict-free), MFMA, direct fp32 global stores.
// LDS 41 KB, launch_bounds(512,6) -> 3 blocks/CU.
// ---------------------------------------------------------------------------
__global__ __launch_bounds__(512, 6) void k_proj(const u16* __restrict__ ain,
                                                 const float* __restrict__ w,
                                                 const float* __restrict__ bias,
                                                 float* __restrict__ outp) {
    extern __shared__ char smem[];
    u16* Bt = (u16*)smem;            // 32 KB swizzled [p][g]
    u16* Sg = Bt + 16384;            // [32][144] staging (9 KB)
    const int h = blockIdx.x, b = blockIdx.y;
    const int t = threadIdx.x;

    // --- staged transpose: 4 phases x 32 ch-rows ---
    const int ldr = t >> 4, ldj8 = t & 15;          // loader: row, col-group
    const int gig = t >> 7, gp = t & 127;           // gather: ch-octet, px
    const u16* gcol = &Sg[(gig * 8) * 144 + gp];
    u16* gdst = Bt + gp * 128;
#pragma unroll
    for (int ph = 0; ph < 4; ++ph) {
        int ch = ph * 32 + ldr;
        *(uint4*)(&Sg[ldr * 144 + ldj8 * 8]) =
            *(const uint4*)(&ain[(((size_t)(b * 128 + ch)) << 14) + (h << 7) + ldj8 * 8]);
        __syncthreads();
        u16 tmp[8];
#pragma unroll
        for (int c = 0; c < 8; ++c) tmp[c] = gcol[c * 144];
        int g = ph * 4 + gig;
        *(uint4*)(gdst + ((g ^ (gp & 15)) << 3)) = *(const uint4*)tmp;
        __syncthreads();
    }

    const int wave = t >> 6, lane = t & 63, m16 = lane & 15, quad = lane >> 4;
    bf16x8 afr[4];
    {
        const float* wp0 = w + (size_t)(wave * 16 + m16) * 128 + quad * 8;
#pragma unroll
        for (int kk = 0; kk < 4; ++kk) {
            float4 w0 = *(const float4*)(wp0 + kk * 32);
            float4 w1 = *(const float4*)(wp0 + kk * 32 + 4);
            bf16x8 a;
            a[0] = (short)f2bf(w0.x); a[1] = (short)f2bf(w0.y);
            a[2] = (short)f2bf(w0.z); a[3] = (short)f2bf(w0.w);
            a[4] = (short)f2bf(w1.x); a[5] = (short)f2bf(w1.y);
            a[6] = (short)f2bf(w1.z); a[7] = (short)f2bf(w1.w);
            afr[kk] = a;
        }
    }

    f32x4 acc[8] = {};
#pragma unroll
    for (int kk = 0; kk < 4; ++kk) {
        const int g = kk * 4 + quad;
#pragma unroll
        for (int nt = 0; nt < 8; ++nt) {
            int p = nt * 16 + m16;
            bf16x8 bf = *(const bf16x8*)(&Bt[p * 128 + ((g ^ (p & 15)) << 3)]);
            acc[nt] = MFMA16(afr[kk], bf, acc[nt]);
        }
    }

    float bv[4];
#pragma unroll
    for (int r = 0; r < 4; ++r) bv[r] = bias[wave * 16 + quad * 4 + r];
    // direct fp32 stores: out[b][co][h][p], 64-B segments per (quad, nt)
    float* ob = outp + (((size_t)(b * 128)) << 14) + (h << 7);
#pragma unroll
    for (int nt = 0; nt < 8; ++nt) {
        int p = nt * 16 + m16;
#pragma unroll
        for (int r = 0; r < 4; ++r) {
            int co = wave * 16 + quad * 4 + r;
            ob[((size_t)co << 14) + p] = acc[nt][r] + bv[r];
        }
    }
}

// ---------------------------------------------------------------------------
extern "C" void kernel_launch(void* const* d_in, const int* in_sizes, int n_in,
                              void* d_out, int out_size, void* d_ws, size_t ws_size,
                              hipStream_t stream) {
    const float* x      = (const float*)d_in[0];
    const float* qkv_w  = (const float*)d_in[1];
    const float* qkv_b  = (const float*)d_in[2];
    const float* dw_w   = (const float*)d_in[3];
    const float* dw_b   = (const float*)d_in[4];
    const float* proj_w = (const float*)d_in[5];
    const float* proj_b = (const float*)d_in[6];
    const float* temp   = (const float*)d_in[7];
    float* out = (float*)d_out;

    u16* buf1 = (u16*)d_ws;
    u16* buf2 = buf1 + (size_t)8 * 384 * 16384;

    hipFuncSetAttribute((const void*)k_qkv,  hipFuncAttributeMaxDynamicSharedMemorySize, 67584);
    hipFuncSetAttribute((const void*)k_attn, hipFuncAttributeMaxDynamicSharedMemorySize, 77824);
    hipFuncSetAttribute((const void*)k_proj, hipFuncAttributeMaxDynamicSharedMemorySize, 41984);

    k_xpose<<<dim3(128, 8), 256, 0, stream>>>(x, buf2);
    k_qkv<<<dim3(128, 8), 512, 67584, stream>>>(buf2, qkv_w, qkv_b, buf1);
    k_dw<<<dim3(4, 384, 8), 256, 0, stream>>>(buf1, dw_w, dw_b, buf2);
    k_attn<<<dim3(128, 8), 512, 77824, stream>>>(buf2, temp, buf1);
    k_proj<<<dim3(128, 8), 512, 41984, stream>>>(buf1, proj_w, proj_b, out);
}

// Round 7
// 254.654 us; speedup vs baseline: 1.0213x; 1.0213x over previous
//
#include <hip/hip_runtime.h>

typedef unsigned short u16;
typedef unsigned int   u32;

typedef short bf16x8 __attribute__((ext_vector_type(8)));
typedef float f32x4  __attribute__((ext_vector_type(4)));

__device__ __forceinline__ float bf2f(u16 u) { return __uint_as_float(((u32)u) << 16); }
__device__ __forceinline__ u16 f2bf(float f) {
    u32 u = __float_as_uint(f);
    return (u16)((u + 0x7fffu + ((u >> 16) & 1u)) >> 16);
}

#define MFMA16(a, b, c) __builtin_amdgcn_mfma_f32_16x16x32_bf16(a, b, c, 0, 0, 0)

// ---------------------------------------------------------------------------
// K0: transpose x[b][ci][p] fp32 -> xT[b][p][ci] bf16.
// ---------------------------------------------------------------------------
__global__ __launch_bounds__(256, 4) void k_xpose(const float* __restrict__ x,
                                                  u16* __restrict__ xT) {
    __shared__ u16 Xs[128 * 128];
    const int ptile = blockIdx.x, b = blockIdx.y;
    const int t = threadIdx.x;
    const float* xb = x + (((size_t)b) << 21) + ptile * 128;
#pragma unroll
    for (int i = 0; i < 16; ++i) {
        int idx = i * 256 + t;
        int ci = idx >> 5, pq = idx & 31;
        float4 v = *(const float4*)(xb + (((size_t)ci) << 14) + pq * 4);
        u32 lo = (u32)f2bf(v.x) | ((u32)f2bf(v.y) << 16);
        u32 hi = (u32)f2bf(v.z) | ((u32)f2bf(v.w) << 16);
        uint2 pk; pk.x = lo; pk.y = hi;
        int cq = ci >> 3;
        *(uint2*)(&Xs[ci * 128 + ((pq ^ cq) << 2)]) = pk;
    }
    __syncthreads();
    u16* ob = xT + (((size_t)b) << 21) + ((size_t)(ptile * 128)) * 128;
#pragma unroll
    for (int j = 0; j < 8; ++j) {
        int p = j * 16 + (t >> 4), cq = t & 15;
        u16 tmp[8];
#pragma unroll
        for (int c = 0; c < 8; ++c) {
            int ci = cq * 8 + c;
            tmp[c] = Xs[ci * 128 + (((p >> 2) ^ cq) << 2) + (p & 3)];
        }
        *(uint4*)(&ob[(size_t)p * 128 + cq * 8]) = *(const uint4*)tmp;
    }
}

// ---------------------------------------------------------------------------
// K1 v3: qkv 1x1 conv from xT (R5 shape: block = (h, cg, b)), with Cs staged
// in two co-halves -> LDS 49 KB -> 3 blocks/CU.
// ---------------------------------------------------------------------------
__global__ __launch_bounds__(512, 6) void k_qkv(const u16* __restrict__ xT,
                                                const float* __restrict__ w,
                                                const float* __restrict__ bias,
                                                u16* __restrict__ out1) {
    extern __shared__ char smem[];
    u16* Bt = (u16*)smem;            // 32 KB swizzled [p][g]
    u16* Cs = Bt + 2048 * 8;         // [64 co][136 p] = 17 KB
    const int h = blockIdx.x, cg = blockIdx.y, b = blockIdx.z;
    const int t = threadIdx.x;

    const u16* xb = xT + (((size_t)b) << 21) + ((size_t)(h * 128)) * 128;
#pragma unroll
    for (int i = 0; i < 4; ++i) {
        int slot = i * 512 + t;
        int p = slot >> 4, g = slot & 15;
        int gg = g ^ (p & 15);
        uint4 v = *(const uint4*)(&xb[p * 128 + gg * 8]);
        *(uint4*)(&Bt[slot * 8]) = v;
    }

    const int wave = t >> 6, lane = t & 63, m16 = lane & 15, quad = lane >> 4;
    bf16x8 afr[4];
    {
        const float* wp0 = w + (size_t)(cg * 128 + wave * 16 + m16) * 128 + quad * 8;
#pragma unroll
        for (int kk = 0; kk < 4; ++kk) {
            float4 w0 = *(const float4*)(wp0 + kk * 32);
            float4 w1 = *(const float4*)(wp0 + kk * 32 + 4);
            bf16x8 a;
            a[0] = (short)f2bf(w0.x); a[1] = (short)f2bf(w0.y);
            a[2] = (short)f2bf(w0.z); a[3] = (short)f2bf(w0.w);
            a[4] = (short)f2bf(w1.x); a[5] = (short)f2bf(w1.y);
            a[6] = (short)f2bf(w1.z); a[7] = (short)f2bf(w1.w);
            afr[kk] = a;
        }
    }
    __syncthreads();

    f32x4 acc[8] = {};
#pragma unroll
    for (int kk = 0; kk < 4; ++kk) {
        const int g = kk * 4 + quad;
#pragma unroll
        for (int nt = 0; nt < 8; ++nt) {
            int p = nt * 16 + m16;
            bf16x8 bf = *(const bf16x8*)(&Bt[p * 128 + ((g ^ (p & 15)) << 3)]);
            acc[nt] = MFMA16(afr[kk], bf, acc[nt]);
        }
    }

    float bv[4];
#pragma unroll
    for (int r = 0; r < 4; ++r) bv[r] = bias[cg * 128 + wave * 16 + quad * 4 + r];

    u16* ob = out1 + (((size_t)(b * 384 + cg * 128)) << 14) + (h << 7);

    // --- half 0: waves 0..3 stage co 0..63, all threads write out ---
    if (wave < 4) {
#pragma unroll
        for (int nt = 0; nt < 8; ++nt) {
            int p = nt * 16 + m16;
#pragma unroll
            for (int r = 0; r < 4; ++r)
                Cs[(wave * 16 + quad * 4 + r) * 136 + p] = f2bf(acc[nt][r] + bv[r]);
        }
    }
    __syncthreads();
#pragma unroll
    for (int it = 0; it < 2; ++it) {
        int idx = it * 512 + t;
        int co = idx >> 4, cp = idx & 15;
        *(uint4*)(&ob[((size_t)co << 14) + cp * 8]) = *(const uint4*)(&Cs[co * 136 + cp * 8]);
    }
    __syncthreads();

    // --- half 1: waves 4..7 stage co 64..127 ---
    if (wave >= 4) {
#pragma unroll
        for (int nt = 0; nt < 8; ++nt) {
            int p = nt * 16 + m16;
#pragma unroll
            for (int r = 0; r < 4; ++r)
                Cs[((wave - 4) * 16 + quad * 4 + r) * 136 + p] = f2bf(acc[nt][r] + bv[r]);
        }
    }
    __syncthreads();
    u16* ob2 = ob + ((size_t)64 << 14);
#pragma unroll
    for (int it = 0; it < 2; ++it) {
        int idx = it * 512 + t;
        int co = idx >> 4, cp = idx & 15;
        *(uint4*)(&ob2[((size_t)co << 14) + cp * 8]) = *(const uint4*)(&Cs[co * 136 + cp * 8]);
    }
}

// ---------------------------------------------------------------------------
// K2: depthwise 3x3 (LDS-tiled).
// ---------------------------------------------------------------------------
__global__ __launch_bounds__(256, 4) void k_dw(const u16* __restrict__ in,
                                               const float* __restrict__ w,
                                               const float* __restrict__ bias,
                                               u16* __restrict__ out) {
    __shared__ u16 tile[34 * 144];
    const int htile = blockIdx.x;
    const int ch = blockIdx.y;
    const int b = blockIdx.z;
    const int t = threadIdx.x;
    const u16* base = in + (((size_t)(b * 384 + ch)) << 14);

    if (t < 68) {
        int r = t >> 1, side = t & 1;
        uint4 z = {0, 0, 0, 0};
        *(uint4*)(&tile[r * 144 + side * 136]) = z;
    }
    for (int it = 0; it < 3; ++it) {
        int idx = it * 256 + t;
        if (idx < 544) {
            int r = idx >> 4, cq = idx & 15;
            int y = htile * 32 - 1 + r;
            uint4 v = {0, 0, 0, 0};
            if (y >= 0 && y <= 127) v = *(const uint4*)(base + (y << 7) + cq * 8);
            *(uint4*)(&tile[r * 144 + 8 + cq * 8]) = v;
        }
    }
    float wg[9];
#pragma unroll
    for (int i = 0; i < 9; ++i) wg[i] = w[ch * 9 + i];
    const float bv = bias[ch];
    __syncthreads();

    const int r = t >> 4, cp = t & 15, c0 = cp * 8;
    u16* ob = out + (((size_t)(b * 384 + ch)) << 14) + ((htile * 32) << 7) + c0;
#pragma unroll
    for (int half = 0; half < 2; ++half) {
        const int ro = r + half * 16;
        float acc[8];
#pragma unroll
        for (int c = 0; c < 8; ++c) acc[c] = bv;
#pragma unroll
        for (int dy = 0; dy < 3; ++dy) {
            const u16* row = &tile[(ro + dy) * 144 + 8 + c0];
            float v[10];
            v[0] = bf2f(row[-1]);
            uint4 m = *(const uint4*)row;
            v[1] = bf2f((u16)(m.x & 0xffff)); v[2] = bf2f((u16)(m.x >> 16));
            v[3] = bf2f((u16)(m.y & 0xffff)); v[4] = bf2f((u16)(m.y >> 16));
            v[5] = bf2f((u16)(m.z & 0xffff)); v[6] = bf2f((u16)(m.z >> 16));
            v[7] = bf2f((u16)(m.w & 0xffff)); v[8] = bf2f((u16)(m.w >> 16));
            v[9] = bf2f(row[8]);
#pragma unroll
            for (int dx = 0; dx < 3; ++dx) {
                const float wv = wg[dy * 3 + dx];
#pragma unroll
                for (int c = 0; c < 8; ++c) acc[c] += wv * v[c + dx];
            }
        }
        u32 pk[4];
#pragma unroll
        for (int c2 = 0; c2 < 4; ++c2) {
            u32 lo = f2bf(acc[2 * c2]), hi = f2bf(acc[2 * c2 + 1]);
            pk[c2] = lo | (hi << 16);
        }
        *(uint4*)(ob + (ro << 7)) = *(uint4*)pk;
    }
}

// ---------------------------------------------------------------------------
// K3 v2: per-(b,ch) attention.  512 thr / 8 waves, 76 KB LDS -> 2 blocks/CU.
// ---------------------------------------------------------------------------
__global__ __launch_bounds__(512, 4) void k_attn(const u16* __restrict__ qkv,
                                                 const float* __restrict__ temp,
                                                 u16* __restrict__ outp) {
    extern __shared__ char smem[];
    u16* Qt = (u16*)smem;            // [j][i] swizzled; Pt aliases
    u16* Kt = Qt + 16384;            // [k][i] swizzled; Osh aliases
    u16* Sg = Qt + 32768;            // [32][144] staging
    float* ps = (float*)(smem + 74752);   // [4][128]
    float* rq = (float*)(smem + 76800);   // [128]
    float* rk = (float*)(smem + 77312);   // [128]
    u16* Pt = Qt;
    u16* Osh = Kt;

    const int ch = blockIdx.x, b = blockIdx.y;
    const int head = ch >> 5;
    const int t = threadIdx.x;
    const size_t qoff = ((size_t)(b * 384 + ch)) << 14;
    const size_t koff = ((size_t)(b * 384 + 128 + ch)) << 14;
    const size_t voff = ((size_t)(b * 384 + 256 + ch)) << 14;

    const int wave = t >> 6, lane = t & 63, m16 = lane & 15, quad = lane >> 4;

    bf16x8 vfr[4];
    {
        const u16* vrow = qkv + voff + (size_t)(wave * 16 + m16) * 128 + quad * 8;
#pragma unroll
        for (int kk = 0; kk < 4; ++kk)
            vfr[kk] = *(const bf16x8*)(vrow + kk * 32);
    }

    const int ldr = t >> 4, ldj8 = t & 15;
    const size_t ldsrc = (ldr < 16 ? qoff + (size_t)ldr * 128
                                   : koff + (size_t)(ldr - 16) * 128) + ldj8 * 8;
    const int gmat = t >> 8, gig = (t >> 7) & 1, gj = t & 127;
    const u16* gcol = &Sg[(gmat * 16 + gig * 8) * 144 + gj];
    u16* gdstbase = (gmat ? Kt : Qt) + gj * 128;
    float ssq = 0.f;
#pragma unroll
    for (int p = 0; p < 8; ++p) {
        *(uint4*)(&Sg[ldr * 144 + ldj8 * 8]) = *(const uint4*)(&qkv[ldsrc + (size_t)p * 2048]);
        __syncthreads();
        u16 tmp[8];
#pragma unroll
        for (int c = 0; c < 8; ++c) {
            u16 v = gcol[c * 144];
            tmp[c] = v;
            float f = bf2f(v);
            ssq += f * f;
        }
        int g = p * 2 + gig;
        *(uint4*)(gdstbase + ((g ^ (gj & 15)) << 3)) = *(const uint4*)tmp;
        __syncthreads();
    }
    ps[(gmat * 2 + gig) * 128 + gj] = ssq;
    __syncthreads();
    if (t < 256) {
        int mat = t >> 7, j = t & 127;
        float s = ps[(mat * 2) * 128 + j] + ps[(mat * 2 + 1) * 128 + j];
        float r = 1.0f / fmaxf(sqrtf(s), 1e-12f);
        if (mat == 0) rq[j] = r; else rk[j] = r;
    }
    __syncthreads();

    f32x4 S[8] = {};
#pragma unroll
    for (int kk = 0; kk < 4; ++kk) {
        const int sw = ((kk * 4 + quad) ^ m16) << 3;
        bf16x8 bf = *(const bf16x8*)(&Kt[(wave * 16 + m16) * 128 + sw]);
#pragma unroll
        for (int jt = 0; jt < 8; ++jt) {
            bf16x8 af = *(const bf16x8*)(&Qt[(jt * 16 + m16) * 128 + sw]);
            S[jt] = MFMA16(af, bf, S[jt]);
        }
    }

    const float sc = temp[head] * rk[wave * 16 + m16];
    float vals[8][4];
    float vmax = -1e30f;
#pragma unroll
    for (int jt = 0; jt < 8; ++jt)
#pragma unroll
        for (int r = 0; r < 4; ++r) {
            float v = S[jt][r] * (rq[jt * 16 + quad * 4 + r] * sc);
            vals[jt][r] = v;
            vmax = fmaxf(vmax, v);
        }
    vmax = fmaxf(vmax, __shfl_xor(vmax, 16));
    vmax = fmaxf(vmax, __shfl_xor(vmax, 32));
    float sum = 0.f;
#pragma unroll
    for (int jt = 0; jt < 8; ++jt)
#pragma unroll
        for (int r = 0; r < 4; ++r) {
            float e = __expf(vals[jt][r] - vmax);
            vals[jt][r] = e;
            sum += e;
        }
    sum += __shfl_xor(sum, 16);
    sum += __shfl_xor(sum, 32);
    const float inv = 1.0f / sum;

    __syncthreads();

    {
        const int k = wave * 16 + m16;
        u16* prow = Pt + k * 128;
#pragma unroll
        for (int jt = 0; jt < 8; ++jt)
#pragma unroll
            for (int pr = 0; pr < 2; ++pr) {
                int j0 = jt * 16 + quad * 4 + pr * 2;
                u32 pk = (u32)f2bf(vals[jt][pr * 2] * inv) |
                         ((u32)f2bf(vals[jt][pr * 2 + 1] * inv) << 16);
                *(u32*)(prow + (((j0 >> 3) ^ (k & 15)) << 3) + (j0 & 7)) = pk;
            }
    }
    __syncthreads();

    f32x4 O[8] = {};
#pragma unroll
    for (int kk = 0; kk < 4; ++kk) {
        const int sw = ((kk * 4 + quad) ^ m16) << 3;
#pragma unroll
        for (int nt = 0; nt < 8; ++nt) {
            bf16x8 bf = *(const bf16x8*)(&Pt[(nt * 16 + m16) * 128 + sw]);
            O[nt] = MFMA16(vfr[kk], bf, O[nt]);
        }
    }

#pragma unroll
    for (int nt = 0; nt < 8; ++nt) {
        int k = nt * 16 + m16;
#pragma unroll
        for (int r = 0; r < 4; ++r) {
            int i = wave * 16 + quad * 4 + r;
            Osh[i * 128 + (((k >> 3) ^ (i & 15)) << 3) + (k & 7)] = f2bf(O[nt][r]);
        }
    }
    __syncthreads();

    u16* ob = outp + (((size_t)(b * 128 + ch)) << 14);
#pragma unroll
    for (int it = 0; it < 4; ++it) {
        int idx = it * 512 + t;
        int row = idx >> 4, gk = idx & 15;
        uint4 v = *(const uint4*)(&Osh[row * 128 + ((gk ^ (row & 15)) << 3)]);
        *(uint4*)(&ob[(row << 7) + gk * 8]) = v;
    }
}

// ---------------------------------------------------------------------------
// K4 v2: proj 1x1 conv.  Staged-panel gather transpose + direct fp32 stores.
// ---------------------------------------------------------------------------
__global__ __launch_bounds__(512, 6) void k_proj(const u16* __restrict__ ain,
                                                 const float* __restrict__ w,
                                                 const float* __restrict__ bias,
                                                 float* __restrict__ outp) {
    extern __shared__ char smem[];
    u16* Bt = (u16*)smem;            // 32 KB swizzled [p][g]
    u16* Sg = Bt + 16384;            // [32][144] staging (9 KB)
    const int h = blockIdx.x, b = blockIdx.y;
    const int t = threadIdx.x;

    const int ldr = t >> 4, ldj8 = t & 15;
    const int gig = t >> 7, gp = t & 127;
    const u16* gcol = &Sg[(gig * 8) * 144 + gp];
    u16* gdst = Bt + gp * 128;
#pragma unroll
    for (int ph = 0; ph < 4; ++ph) {
        int ch = ph * 32 + ldr;
        *(uint4*)(&Sg[ldr * 144 + ldj8 * 8]) =
            *(const uint4*)(&ain[(((size_t)(b * 128 + ch)) << 14) + (h << 7) + ldj8 * 8]);
        __syncthreads();
        u16 tmp[8];
#pragma unroll
        for (int c = 0; c < 8; ++c) tmp[c] = gcol[c * 144];
        int g = ph * 4 + gig;
        *(uint4*)(gdst + ((g ^ (gp & 15)) << 3)) = *(const uint4*)tmp;
        __syncthreads();
    }

    const int wave = t >> 6, lane = t & 63, m16 = lane & 15, quad = lane >> 4;
    bf16x8 afr[4];
    {
        const float* wp0 = w + (size_t)(wave * 16 + m16) * 128 + quad * 8;
#pragma unroll
        for (int kk = 0; kk < 4; ++kk) {
            float4 w0 = *(const float4*)(wp0 + kk * 32);
            float4 w1 = *(const float4*)(wp0 + kk * 32 + 4);
            bf16x8 a;
            a[0] = (short)f2bf(w0.x); a[1] = (short)f2bf(w0.y);
            a[2] = (short)f2bf(w0.z); a[3] = (short)f2bf(w0.w);
            a[4] = (short)f2bf(w1.x); a[5] = (short)f2bf(w1.y);
            a[6] = (short)f2bf(w1.z); a[7] = (short)f2bf(w1.w);
            afr[kk] = a;
        }
    }

    f32x4 acc[8] = {};
#pragma unroll
    for (int kk = 0; kk < 4; ++kk) {
        const int g = kk * 4 + quad;
#pragma unroll
        for (int nt = 0; nt < 8; ++nt) {
            int p = nt * 16 + m16;
            bf16x8 bf = *(const bf16x8*)(&Bt[p * 128 + ((g ^ (p & 15)) << 3)]);
            acc[nt] = MFMA16(afr[kk], bf, acc[nt]);
        }
    }

    float bv[4];
#pragma unroll
    for (int r = 0; r < 4; ++r) bv[r] = bias[wave * 16 + quad * 4 + r];
    float* ob = outp + (((size_t)(b * 128)) << 14) + (h << 7);
#pragma unroll
    for (int nt = 0; nt < 8; ++nt) {
        int p = nt * 16 + m16;
#pragma unroll
        for (int r = 0; r < 4; ++r) {
            int co = wave * 16 + quad * 4 + r;
            ob[((size_t)co << 14) + p] = acc[nt][r] + bv[r];
        }
    }
}

// ---------------------------------------------------------------------------
extern "C" void kernel_launch(void* const* d_in, const int* in_sizes, int n_in,
                              void* d_out, int out_size, void* d_ws, size_t ws_size,
                              hipStream_t stream) {
    const float* x      = (const float*)d_in[0];
    const float* qkv_w  = (const float*)d_in[1];
    const float* qkv_b  = (const float*)d_in[2];
    const float* dw_w   = (const float*)d_in[3];
    const float* dw_b   = (const float*)d_in[4];
    const float* proj_w = (const float*)d_in[5];
    const float* proj_b = (const float*)d_in[6];
    const float* temp   = (const float*)d_in[7];
    float* out = (float*)d_out;

    u16* buf1 = (u16*)d_ws;
    u16* buf2 = buf1 + (size_t)8 * 384 * 16384;

    hipFuncSetAttribute((const void*)k_qkv,  hipFuncAttributeMaxDynamicSharedMemorySize, 50176);
    hipFuncSetAttribute((const void*)k_attn, hipFuncAttributeMaxDynamicSharedMemorySize, 77824);
    hipFuncSetAttribute((const void*)k_proj, hipFuncAttributeMaxDynamicSharedMemorySize, 41984);

    k_xpose<<<dim3(128, 8), 256, 0, stream>>>(x, buf2);
    k_qkv<<<dim3(128, 3, 8), 512, 50176, stream>>>(buf2, qkv_w, qkv_b, buf1);
    k_dw<<<dim3(4, 384, 8), 256, 0, stream>>>(buf1, dw_w, dw_b, buf2);
    k_attn<<<dim3(128, 8), 512, 77824, stream>>>(buf2, temp, buf1);
    k_proj<<<dim3(128, 8), 512, 41984, stream>>>(buf1, proj_w, proj_b, out);
}